// Round 4
// baseline (280.804 us; speedup 1.0000x reference)
//
#include <hip/hip_runtime.h>
#include <stdint.h>

// Problem constants: B=8, S=1024, D=1024, H=16, HD=64
#define BB 8
#define SS 1024
#define DD 1024
#define HH 16
#define HDIM 64

typedef __bf16 bf16x8 __attribute__((ext_vector_type(8)));
typedef float f32x4 __attribute__((ext_vector_type(4)));

__device__ __forceinline__ unsigned short f2bf(float f) {
    union { float f; unsigned u; } v; v.f = f;
    unsigned r = v.u + 0x7fff + ((v.u >> 16) & 1);   // RNE
    return (unsigned short)(r >> 16);
}

// round-half-up bf16 pair pack: bf(f1)<<16 | bf(f0)  (1 perm + 2 adds)
__device__ __forceinline__ unsigned pk2bf(float f0, float f1) {
    union { float f; unsigned u; } a, b; a.f = f0; b.f = f1;
    return __builtin_amdgcn_perm(b.u + 0x8000u, a.u + 0x8000u, 0x07060302u);
}

__device__ __forceinline__ float exp2fast(float x) {
#if __has_builtin(__builtin_amdgcn_exp2f)
    return __builtin_amdgcn_exp2f(x);
#else
    return __expf(x * 0.69314718f);
#endif
}

// async global->LDS, 16B per lane (LDS dest: wave-uniform base + lane*16)
__device__ __forceinline__ void async16(void* lds, const void* g) {
    __builtin_amdgcn_global_load_lds(
        (const __attribute__((address_space(1))) unsigned int*)g,
        (__attribute__((address_space(3))) unsigned int*)lds, 16, 0, 0);
}

// ---------------- Kernel 1: prep = convert X + transpose W ----------------
// blocks 0..8191: X fp32->bf16 (1024 elems each)
// blocks 8192..8959: W [K][N] fp32 -> WT [N][K] bf16 (64x64 tiles, 3 mats)
__global__ __launch_bounds__(256) void prep(
    const float* __restrict__ x, unsigned short* __restrict__ xb,
    const float* __restrict__ w0, const float* __restrict__ w1,
    const float* __restrict__ w2,
    unsigned short* __restrict__ t0, unsigned short* __restrict__ t1,
    unsigned short* __restrict__ t2)
{
    __shared__ unsigned short tile[64][65];
    int bid = blockIdx.x;
    if (bid < 8192) {
        int i = (bid * 256 + threadIdx.x) * 4;
        float4 f = *reinterpret_cast<const float4*>(x + i);
        ushort4 o;
        o.x = f2bf(f.x); o.y = f2bf(f.y); o.z = f2bf(f.z); o.w = f2bf(f.w);
        *reinterpret_cast<ushort4*>(xb + i) = o;
        return;
    }
    int idx = bid - 8192;                      // 0..767
    int z = idx >> 8, rem = idx & 255;
    const float* w = (z == 0) ? w0 : (z == 1) ? w1 : w2;
    unsigned short* wt = (z == 0) ? t0 : (z == 1) ? t1 : t2;
    int k0 = (rem & 15) * 64, n0 = (rem >> 4) * 64;
    #pragma unroll
    for (int i = 0; i < 16; ++i) {
        int id = threadIdx.x + i * 256;
        int r = id >> 6, c = id & 63;
        tile[r][c] = f2bf(w[(k0 + r) * DD + n0 + c]);
    }
    __syncthreads();
    #pragma unroll
    for (int i = 0; i < 16; ++i) {
        int id = threadIdx.x + i * 256;
        int r = id >> 6, c = id & 63;          // r: n-offset, c: k-offset
        wt[(n0 + r) * DD + k0 + c] = tile[c][r];
    }
}

// ---------------- Kernel 2: fused QKV GEMM (A-in-regs, B-in-LDS) ----------
// 128x128 tile, BK=32, 32 iters. A-frags global->VGPR (reg dbuf, 1-iter
// prefetch, fine-grained vmcnt). B staged via global_load_lds (LDS dbuf,
// one barrier/iter, 8KB/iter). XCD swizzle keeps each XCD's 3 B-strips
// L2-resident. V written transposed [bh][hd][s].
__global__ __launch_bounds__(256) void gemm_qkv(
    const unsigned short* __restrict__ xb,
    const unsigned short* __restrict__ wt0, const unsigned short* __restrict__ wt1,
    const unsigned short* __restrict__ wt2,
    const float* __restrict__ b0, const float* __restrict__ b1, const float* __restrict__ b2,
    unsigned short* __restrict__ qo, unsigned short* __restrict__ ko,
    unsigned short* __restrict__ vto)
{
    // linear grid 1536; xcd = bid&7; each XCD owns 3 (n,z) B-strips
    int bid = blockIdx.x;
    int xcd = bid & 7, g = bid >> 3;           // g 0..191
    int strip = xcd * 3 + (g % 3);             // 0..23
    int mt = g / 3;                            // 0..63
    int nt = strip & 7, z = strip >> 3;

    const unsigned short* wt; const float* bias; unsigned short* out;
    if (z == 0)      { wt = wt0; bias = b0; out = qo; }
    else if (z == 1) { wt = wt1; bias = b1; out = ko; }
    else             { wt = wt2; bias = b2; out = vto; }

    __shared__ unsigned short Bs[2][128 * 32];

    int m0 = mt * 128, n0 = nt * 128;
    int tid = threadIdx.x;
    int wave = tid >> 6, lane = tid & 63, lq = lane >> 4, lm = lane & 15;
    int wr = wave >> 1, wc = wave & 1;         // 2x2 wave grid, each 64x64

    f32x4 acc[4][4] = {};

    // B staging: slot tid -> (row=tid>>2, s=tid&3); chunk swizzle (c+(r>>1))&3
    int row0 = tid >> 2, s4 = tid & 3;
    int c0 = (s4 - (row0 >> 1)) & 3;
    const unsigned short* gb0 = wt + (n0 + row0) * DD + c0 * 8;
    const unsigned short* gb1 = gb0 + 64 * DD;

    // A direct loads: thread (lq,lm) row = m0 + wr*64 + i*16 + lm, k = t*32+lq*8
    const unsigned short* aBase = xb + (m0 + wr * 64 + lm) * DD + lq * 8;

    int slot = ((lq + (lm >> 1)) & 3) * 8;     // B frag-read swizzled offset

    bf16x8 a[2][4];

    async16(&Bs[0][tid * 8], gb0);
    async16(&Bs[0][(tid + 256) * 8], gb1);
    #pragma unroll
    for (int i = 0; i < 4; ++i)
        a[0][i] = *reinterpret_cast<const bf16x8*>(aBase + i * 16 * DD);

    #pragma unroll
    for (int t = 0; t < 32; ++t) {
        int p = t & 1;
        __syncthreads();
        if (t < 31) {
            async16(&Bs[p ^ 1][tid * 8], gb0 + (t + 1) * 32);
            async16(&Bs[p ^ 1][(tid + 256) * 8], gb1 + (t + 1) * 32);
            #pragma unroll
            for (int i = 0; i < 4; ++i)
                a[p ^ 1][i] = *reinterpret_cast<const bf16x8*>(aBase + i * 16 * DD + (t + 1) * 32);
        }
        bf16x8 b[4];
        #pragma unroll
        for (int j = 0; j < 4; ++j)
            b[j] = *reinterpret_cast<const bf16x8*>(&Bs[p][(wc * 64 + j * 16 + lm) * 32 + slot]);
        #pragma unroll
        for (int i = 0; i < 4; ++i)
            #pragma unroll
            for (int j = 0; j < 4; ++j)
                acc[i][j] = __builtin_amdgcn_mfma_f32_16x16x32_bf16(a[p][i], b[j], acc[i][j], 0, 0, 0);
    }

    if (z == 2) {
        // V^T epilogue: [bh][hd][s]; 4 consecutive s per thread -> ushort4
        #pragma unroll
        for (int j = 0; j < 4; ++j) {
            int col = n0 + wc * 64 + j * 16 + lm;
            float bsv = bias[col];
            int h = col >> 6, hd = col & 63;
            #pragma unroll
            for (int i = 0; i < 4; ++i) {
                int m = m0 + wr * 64 + i * 16 + lq * 4;
                int b_ = m >> 10, sr = m & 1023;
                uint2 pk;
                pk.x = pk2bf(acc[i][j][0] + bsv, acc[i][j][1] + bsv);
                pk.y = pk2bf(acc[i][j][2] + bsv, acc[i][j][3] + bsv);
                *reinterpret_cast<uint2*>(out + (((b_ * HH + h) * HDIM + hd) << 10) + sr) = pk;
            }
        }
    } else {
        #pragma unroll
        for (int j = 0; j < 4; ++j) {
            int col = n0 + wc * 64 + j * 16 + lm;
            float bsv = bias[col];
            int h = col >> 6, hd = col & 63;
            #pragma unroll
            for (int i = 0; i < 4; ++i) {
                #pragma unroll
                for (int r = 0; r < 4; ++r) {
                    int m = m0 + wr * 64 + i * 16 + lq * 4 + r;
                    int b_ = m >> 10, sr = m & 1023;
                    union { float f; unsigned u; } cv; cv.f = acc[i][j][r] + bsv;
                    out[(((b_ * HH + h) << 10) + sr) * HDIM + hd] =
                        (unsigned short)((cv.u + 0x8000u) >> 16);
                }
            }
        }
    }
}

// ---------------- Kernel 3: flash attention v4 ----------------
// 64 q-rows/block, 4 waves x 16 rows, Kt=64. Transposed score MFMA.
// 40 KB LDS exactly -> 4 blocks/CU. P write->read stall covered by
// interleaving independent score MFMAs. Mask read direct from global.
__global__ __launch_bounds__(256) void attention(
    const unsigned short* __restrict__ q,     // [bh][s][hd]
    const unsigned short* __restrict__ k,     // [bh][s][hd]
    const unsigned short* __restrict__ vt,    // [bh][hd][s]
    const float* __restrict__ mask,
    float* __restrict__ out)
{
    __shared__ unsigned short Ks[2][64 * 64];   // [key][hd], swizzled chunks
    __shared__ unsigned short Vs[2][64 * 64];   // [hd][key], swizzled chunks
    __shared__ unsigned short Ps[4][16 * 64];   // per-wave P[q][key], swizzled

    // XCD swizzle: all 16 q-tiles of a (b,h) on one XCD
    int blk = blockIdx.x;
    int xcd = blk & 7, j = blk >> 3;
    int bh = (xcd << 4) + (j >> 4);
    int qt = j & 15;
    int b = bh >> 4, h = bh & 15;

    int tid = threadIdx.x;
    int wave = tid >> 6, lane = tid & 63, lq = lane >> 4, lm = lane & 15;

    const unsigned short* qp = q + (size_t)bh * SS * HDIM;
    const unsigned short* kp = k + (size_t)bh * SS * HDIM;
    const unsigned short* vp = vt + (size_t)bh * HDIM * SS;
    const float* maskb = mask + b * SS;

    // Q fragments (B-operand: B[k=lq*8+j][n=lm] = Q[qrow=lm][hd=lq*8+j])
    int qrow = qt * 64 + wave * 16 + lm;
    bf16x8 qa0 = *reinterpret_cast<const bf16x8*>(qp + qrow * HDIM + lq * 8);
    bf16x8 qa1 = *reinterpret_cast<const bf16x8*>(qp + qrow * HDIM + 32 + lq * 8);

    float lsum = 0.f;
    f32x4 o[4] = {};

    // staging: slot tid -> (row=tid>>3, s=tid&7); +256 -> row+32 (32%8==0:
    // same chunk offset works). chunk swizzle (c + row) & 7.
    int row0 = tid >> 3, sg = tid & 7;
    int cg = (sg - row0) & 7;
    const unsigned short* gk = kp + row0 * 64 + cg * 8;
    const unsigned short* gv = vp + row0 * SS + cg * 8;

    int sl0 = ((lq + lm) & 7) * 8;              // Ks/Vs frag offsets (ks=0)
    int sl1 = ((lq + lm + 4) & 7) * 8;          // (ks=1)
    unsigned short* Pw = Ps[wave];
    // P write addr (per nb): chunk nb*2+(lq>>1), slot (c+lm)&7, half (lq&1)
    int pwbase = lm * 64 + (lq & 1) * 4;
    // P read addr (per ks): chunk ks*4+lq -> full chunk b128
    int prd0 = lm * 64 + sl0;
    int prd1 = lm * 64 + sl1;

    async16(&Ks[0][tid * 8], gk);  async16(&Ks[0][(tid + 256) * 8], gk + 32 * 64);
    async16(&Vs[0][tid * 8], gv);  async16(&Vs[0][(tid + 256) * 8], gv + 32 * SS);
    gk += 64 * 64; gv += 64;

    for (int t = 0; t < 16; ++t) {
        int p = t & 1;
        __syncthreads();
        if (t < 15) {
            async16(&Ks[p ^ 1][tid * 8], gk);  async16(&Ks[p ^ 1][(tid + 256) * 8], gk + 32 * 64);
            async16(&Vs[p ^ 1][tid * 8], gv);  async16(&Vs[p ^ 1][(tid + 256) * 8], gv + 32 * SS);
            gk += 64 * 64; gv += 64;
        }
        int kb0 = t * 64;

        // mask values (L2-hot, issued early)
        float4 mk[4];
        #pragma unroll
        for (int nb = 0; nb < 4; ++nb)
            mk[nb] = *reinterpret_cast<const float4*>(maskb + kb0 + nb * 16 + lq * 4);

        // scores St = K*Q^T, key-blocks 0,1
        f32x4 c[4];
        #pragma unroll
        for (int nb = 0; nb < 2; ++nb) {
            bf16x8 kf0 = *reinterpret_cast<const bf16x8*>(&Ks[p][(nb * 16 + lm) * 64 + sl0]);
            bf16x8 kf1 = *reinterpret_cast<const bf16x8*>(&Ks[p][(nb * 16 + lm) * 64 + sl1]);
            f32x4 zz = {};
            zz = __builtin_amdgcn_mfma_f32_16x16x32_bf16(kf0, qa0, zz, 0, 0, 0);
            zz = __builtin_amdgcn_mfma_f32_16x16x32_bf16(kf1, qa1, zz, 0, 0, 0);
            c[nb] = zz;
        }
        // softmax + P-writes for nb 0,1
        #pragma unroll
        for (int nb = 0; nb < 2; ++nb) {
            unsigned u[4];
            #pragma unroll
            for (int r = 0; r < 4; ++r) {
                float e = exp2fast(fmaf(c[nb][r], 0.18033688f,
                                        reinterpret_cast<const float*>(&mk[nb])[r] * 1.44269504f));
                union { float f; unsigned v; } cv; cv.f = e;
                u[r] = cv.v + 0x8000u;
                union { unsigned v; float f; } tr; tr.v = u[r] & 0xffff0000u;
                lsum += tr.f;                   // lsum of the ROUNDED p (exact cancel)
            }
            uint2 pk;
            pk.x = __builtin_amdgcn_perm(u[1], u[0], 0x07060302u);
            pk.y = __builtin_amdgcn_perm(u[3], u[2], 0x07060302u);
            *reinterpret_cast<uint2*>(
                &Pw[pwbase + (((nb * 2 + (lq >> 1)) + lm) & 7) * 8]) = pk;
        }
        // scores key-blocks 2,3 (covers P write->read latency)
        #pragma unroll
        for (int nb = 2; nb < 4; ++nb) {
            bf16x8 kf0 = *reinterpret_cast<const bf16x8*>(&Ks[p][(nb * 16 + lm) * 64 + sl0]);
            bf16x8 kf1 = *reinterpret_cast<const bf16x8*>(&Ks[p][(nb * 16 + lm) * 64 + sl1]);
            f32x4 zz = {};
            zz = __builtin_amdgcn_mfma_f32_16x16x32_bf16(kf0, qa0, zz, 0, 0, 0);
            zz = __builtin_amdgcn_mfma_f32_16x16x32_bf16(kf1, qa1, zz, 0, 0, 0);
            c[nb] = zz;
        }
        // PV ks=0 (keys 0..31, from nb 0,1 writes)
        {
            bf16x8 pa = *reinterpret_cast<const bf16x8*>(&Pw[prd0]);
            #pragma unroll
            for (int nb2 = 0; nb2 < 4; ++nb2) {
                bf16x8 vf = *reinterpret_cast<const bf16x8*>(&Vs[p][(nb2 * 16 + lm) * 64 + sl0]);
                o[nb2] = __builtin_amdgcn_mfma_f32_16x16x32_bf16(pa, vf, o[nb2], 0, 0, 0);
            }
        }
        // softmax + P-writes for nb 2,3
        #pragma unroll
        for (int nb = 2; nb < 4; ++nb) {
            unsigned u[4];
            #pragma unroll
            for (int r = 0; r < 4; ++r) {
                float e = exp2fast(fmaf(c[nb][r], 0.18033688f,
                                        reinterpret_cast<const float*>(&mk[nb])[r] * 1.44269504f));
                union { float f; unsigned v; } cv; cv.f = e;
                u[r] = cv.v + 0x8000u;
                union { unsigned v; float f; } tr; tr.v = u[r] & 0xffff0000u;
                lsum += tr.f;
            }
            uint2 pk;
            pk.x = __builtin_amdgcn_perm(u[1], u[0], 0x07060302u);
            pk.y = __builtin_amdgcn_perm(u[3], u[2], 0x07060302u);
            *reinterpret_cast<uint2*>(
                &Pw[pwbase + (((nb * 2 + (lq >> 1)) + lm) & 7) * 8]) = pk;
        }
        // PV ks=1 (keys 32..63)
        {
            bf16x8 pa = *reinterpret_cast<const bf16x8*>(&Pw[prd1]);
            #pragma unroll
            for (int nb2 = 0; nb2 < 4; ++nb2) {
                bf16x8 vf = *reinterpret_cast<const bf16x8*>(&Vs[p][(nb2 * 16 + lm) * 64 + sl1]);
                o[nb2] = __builtin_amdgcn_mfma_f32_16x16x32_bf16(pa, vf, o[nb2], 0, 0, 0);
            }
        }
    }

    // lsum (q=lm) lives in 4 lq-copies: reduce across lq, fetch per out-row
    lsum += __shfl_xor(lsum, 16, 64);
    lsum += __shfl_xor(lsum, 32, 64);
    float linv[4];
    #pragma unroll
    for (int r = 0; r < 4; ++r)
        linv[r] = 1.0f / __shfl(lsum, lq * 4 + r, 64);

    #pragma unroll
    for (int nb2 = 0; nb2 < 4; ++nb2) {
        #pragma unroll
        for (int r = 0; r < 4; ++r) {
            int sr = qt * 64 + wave * 16 + lq * 4 + r;
            out[((size_t)(b * SS + sr)) * DD + h * HDIM + nb2 * 16 + lm] = o[nb2][r] * linv[r];
        }
    }
}

extern "C" void kernel_launch(void* const* d_in, const int* in_sizes, int n_in,
                              void* d_out, int out_size, void* d_ws, size_t ws_size,
                              hipStream_t stream) {
    const float* hs   = (const float*)d_in[0];
    const float* mask = (const float*)d_in[1];
    const float* Wq   = (const float*)d_in[2];
    const float* bq   = (const float*)d_in[3];
    const float* Wk   = (const float*)d_in[4];
    const float* bk   = (const float*)d_in[5];
    const float* Wv   = (const float*)d_in[6];
    const float* bv   = (const float*)d_in[7];
    float* out = (float*)d_out;

    char* ws = (char*)d_ws;
    // ws layout (bytes): Xb 16MB | WT0/1/2 2MB each | q,k,vt 16MB each = 70MB
    unsigned short* Xb  = (unsigned short*)(ws);
    unsigned short* WT0 = (unsigned short*)(ws + 16777216);
    unsigned short* WT1 = (unsigned short*)(ws + 18874368);
    unsigned short* WT2 = (unsigned short*)(ws + 20971520);
    unsigned short* qw  = (unsigned short*)(ws + 23068672);
    unsigned short* kw  = (unsigned short*)(ws + 39845888);
    unsigned short* vtw = (unsigned short*)(ws + 56623104);

    prep<<<8960, 256, 0, stream>>>(hs, Xb, Wq, Wk, Wv, WT0, WT1, WT2);
    gemm_qkv<<<1536, 256, 0, stream>>>(Xb, WT0, WT1, WT2,
                                       bq, bk, bv, qw, kw, vtw);
    attention<<<2048, 256, 0, stream>>>(qw, kw, vtw, mask, out);
}

// Round 5
// 232.621 us; speedup vs baseline: 1.2071x; 1.2071x over previous
//
#include <hip/hip_runtime.h>
#include <stdint.h>

// Problem constants: B=8, S=1024, D=1024, H=16, HD=64
#define BB 8
#define SS 1024
#define DD 1024
#define HH 16
#define HDIM 64

typedef __bf16 bf16x8 __attribute__((ext_vector_type(8)));
typedef float f32x4 __attribute__((ext_vector_type(4)));

__device__ __forceinline__ unsigned short f2bf(float f) {
    union { float f; unsigned u; } v; v.f = f;
    unsigned r = v.u + 0x7fff + ((v.u >> 16) & 1);   // RNE
    return (unsigned short)(r >> 16);
}

__device__ __forceinline__ float exp2fast(float x) {
#if __has_builtin(__builtin_amdgcn_exp2f)
    return __builtin_amdgcn_exp2f(x);
#else
    return __expf(x * 0.69314718f);
#endif
}

// async global->LDS, 16B per lane (LDS dest: wave-uniform base + lane*16)
__device__ __forceinline__ void async16(void* lds, const void* g) {
    __builtin_amdgcn_global_load_lds(
        (const __attribute__((address_space(1))) unsigned int*)g,
        (__attribute__((address_space(3))) unsigned int*)lds, 16, 0, 0);
}

// ================= Kernel 1: prep =================
// Pre-fragment X and W^T into MFMA-fragment order:
//   frag (fm, fk) of M[m][k]: element (m,k) -> lane = ((k>>3)&3)*16 + (m&15),
//   byte j = k&7; fragment = contiguous 1KB at ((fm*32+fk)*64 + lane)*8 elems.
// blocks 0..2047: X (128 mt x 16 kt, 64x64 tiles)
// blocks 2048..2815: W (3 mats x 256 tiles); frag rows are N (i.e. W^T).
__global__ __launch_bounds__(256) void prep(
    const float* __restrict__ x, unsigned short* __restrict__ xf,
    const float* __restrict__ w0, const float* __restrict__ w1,
    const float* __restrict__ w2,
    unsigned short* __restrict__ f0, unsigned short* __restrict__ f1,
    unsigned short* __restrict__ f2)
{
    __shared__ unsigned short tile[64 * 76];
    int bid = blockIdx.x;
    int tid = threadIdx.x;
    if (bid < 2048) {
        int mt = bid >> 4, kt = bid & 15;
        const float* src = x + (size_t)(mt * 64) * DD + kt * 64;
        #pragma unroll
        for (int i = 0; i < 4; ++i) {
            int f = tid + i * 256;              // 64 rows x 16 float4
            int r = f >> 4, c4 = f & 15;
            float4 v = *reinterpret_cast<const float4*>(src + r * DD + c4 * 4);
            ushort4 o;
            o.x = f2bf(v.x); o.y = f2bf(v.y); o.z = f2bf(v.z); o.w = f2bf(v.w);
            *reinterpret_cast<ushort4*>(&tile[r * 76 + c4 * 4]) = o;
        }
        __syncthreads();
        #pragma unroll
        for (int i = 0; i < 2; ++i) {
            int s = tid + i * 256;
            int frag = s >> 6, l = s & 63;
            int m_l = (frag & 3) * 16 + (l & 15);
            int k_l = (frag >> 2) * 32 + ((l >> 4) & 3) * 8;
            uint4 v = *reinterpret_cast<const uint4*>(&tile[m_l * 76 + k_l]);
            int fm = mt * 4 + (frag & 3);
            int fk = kt * 2 + (frag >> 2);
            *reinterpret_cast<uint4*>(xf + (size_t)((fm * 32 + fk) * 64 + l) * 8) = v;
        }
        return;
    }
    int idx = bid - 2048;                       // 0..767
    int z = idx >> 8, rem = idx & 255;
    const float* w = (z == 0) ? w0 : (z == 1) ? w1 : w2;
    unsigned short* wf = (z == 0) ? f0 : (z == 1) ? f1 : f2;
    int kt = rem & 15, nt = rem >> 4;
    const float* src = w + (size_t)(kt * 64) * DD + nt * 64;
    // stage tile[k][n] (coalesced read, coalesced LDS store)
    #pragma unroll
    for (int i = 0; i < 4; ++i) {
        int f = tid + i * 256;
        int r = f >> 4, c4 = f & 15;            // r = k, c4 = n/4
        float4 v = *reinterpret_cast<const float4*>(src + r * DD + c4 * 4);
        ushort4 o;
        o.x = f2bf(v.x); o.y = f2bf(v.y); o.z = f2bf(v.z); o.w = f2bf(v.w);
        *reinterpret_cast<ushort4*>(&tile[r * 76 + c4 * 4]) = o;
    }
    __syncthreads();
    // fragment rows are N: frag element (n,k) -> needs tile[k+j][n] (scalar)
    #pragma unroll
    for (int i = 0; i < 2; ++i) {
        int s = tid + i * 256;
        int frag = s >> 6, l = s & 63;
        int n_l = (frag & 3) * 16 + (l & 15);
        int k_l = (frag >> 2) * 32 + ((l >> 4) & 3) * 8;
        unsigned short tmp[8];
        #pragma unroll
        for (int j = 0; j < 8; ++j) tmp[j] = tile[(k_l + j) * 76 + n_l];
        int fn = nt * 4 + (frag & 3);
        int fk = kt * 2 + (frag >> 2);
        *reinterpret_cast<uint4*>(wf + (size_t)((fn * 32 + fk) * 64 + l) * 8) =
            *reinterpret_cast<const uint4*>(tmp);
    }
}

// ================= Kernel 2: fused QKV GEMM (fragment-direct, no LDS staging)
// 128x128 tile, 2x2 waves of 64x64. All frags loaded global->VGPR as
// contiguous 1KB coalesced dwordx4; register double-buffer 1 iter ahead;
// NO barriers in the K-loop. XCD swizzle: each XCD owns 3 (nt,z) B-strips
// (768KB, L2-resident) and its 3 co-resident blocks share the same A-tile.
__global__ __launch_bounds__(256, 3) void gemm_qkv(
    const unsigned short* __restrict__ xf,
    const unsigned short* __restrict__ wf0, const unsigned short* __restrict__ wf1,
    const unsigned short* __restrict__ wf2,
    const float* __restrict__ b0, const float* __restrict__ b1, const float* __restrict__ b2,
    unsigned short* __restrict__ qo, unsigned short* __restrict__ ko,
    unsigned short* __restrict__ vto)
{
    int bid = blockIdx.x;
    int xcd = bid & 7, g = bid >> 3;           // g 0..191
    int strip = xcd * 3 + (g % 3);             // 0..23
    int mt = g / 3;                            // 0..63
    int nt = strip & 7, z = strip >> 3;

    const unsigned short* wf; const float* bias; unsigned short* out;
    if (z == 0)      { wf = wf0; bias = b0; out = qo; }
    else if (z == 1) { wf = wf1; bias = b1; out = ko; }
    else             { wf = wf2; bias = b2; out = vto; }

    __shared__ unsigned short stg[4][64 * 76];  // epilogue staging only

    int tid = threadIdx.x;
    int wave = tid >> 6, lane = tid & 63, lq = lane >> 4, lm = lane & 15;
    int wr = wave >> 1, wc = wave & 1;

    // frag bases: frag (i,t) at base + (i*32 + t)*512 elems
    const unsigned short* aB = xf + (size_t)((mt * 8 + wr * 4) * 32) * 512 + lane * 8;
    const unsigned short* bB = wf + (size_t)((nt * 8 + wc * 4) * 32) * 512 + lane * 8;

    f32x4 acc[4][4] = {};
    bf16x8 a0[4], a1[4], bb0[4], bb1[4];

#define LDFRAGS(AB, BB, T)                                                     \
    {                                                                          \
        _Pragma("unroll") for (int i_ = 0; i_ < 4; ++i_)                       \
            AB[i_] = *reinterpret_cast<const bf16x8*>(aB + (i_ * 32 + (T)) * 512); \
        _Pragma("unroll") for (int j_ = 0; j_ < 4; ++j_)                       \
            BB[j_] = *reinterpret_cast<const bf16x8*>(bB + (j_ * 32 + (T)) * 512); \
    }
#define MFMAS(AB, BB)                                                          \
    {                                                                          \
        _Pragma("unroll") for (int i_ = 0; i_ < 4; ++i_)                       \
            _Pragma("unroll") for (int j_ = 0; j_ < 4; ++j_)                   \
                acc[i_][j_] = __builtin_amdgcn_mfma_f32_16x16x32_bf16(         \
                    AB[i_], BB[j_], acc[i_][j_], 0, 0, 0);                     \
    }

    LDFRAGS(a0, bb0, 0);
    for (int tt = 0; tt < 16; ++tt) {
        int t = tt * 2;
        LDFRAGS(a1, bb1, t + 1);
        MFMAS(a0, bb0);
        LDFRAGS(a0, bb0, t + 2);   // tt=15 loads t=32: harmless in-ws garbage, unused
        MFMAS(a1, bb1);
    }
#undef LDFRAGS
#undef MFMAS

    int m0 = mt * 128;
    int col0 = nt * 128 + wc * 64;              // this wave's 64-col block = one head
    if (z == 2) {
        // V^T: [bh][hd][s]; 4 consecutive s per thread -> uint2
        #pragma unroll
        for (int j = 0; j < 4; ++j) {
            int col = col0 + j * 16 + lm;
            float bsv = bias[col];
            int h = col >> 6, hd = col & 63;
            #pragma unroll
            for (int i = 0; i < 4; ++i) {
                int m = m0 + wr * 64 + i * 16 + lq * 4;
                int b_ = m >> 10, sr = m & 1023;
                union { float f; unsigned u; } p0, p1, p2, p3;
                p0.f = acc[i][j][0] + bsv; p1.f = acc[i][j][1] + bsv;
                p2.f = acc[i][j][2] + bsv; p3.f = acc[i][j][3] + bsv;
                uint2 pk;
                pk.x = __builtin_amdgcn_perm(p1.u + 0x8000u, p0.u + 0x8000u, 0x07060302u);
                pk.y = __builtin_amdgcn_perm(p3.u + 0x8000u, p2.u + 0x8000u, 0x07060302u);
                *reinterpret_cast<uint2*>(out + (((b_ * HH + h) * HDIM + hd) << 10) + sr) = pk;
            }
        }
    } else {
        // q/k: [bh][s][hd]; stage wave's 64x64 tile in LDS, write 1KB rows
        unsigned short* S = stg[wave];
        #pragma unroll
        for (int j = 0; j < 4; ++j) {
            float bsv = bias[col0 + j * 16 + lm];
            #pragma unroll
            for (int i = 0; i < 4; ++i) {
                #pragma unroll
                for (int r = 0; r < 4; ++r) {
                    union { float f; unsigned u; } cv; cv.f = acc[i][j][r] + bsv;
                    S[(i * 16 + lq * 4 + r) * 76 + j * 16 + lm] =
                        (unsigned short)((cv.u + 0x8000u) >> 16);
                }
            }
        }
        // same-wave ds_write -> ds_read: in-order DS pipe, no barrier needed
        int h = col0 >> 6;
        int mrow = m0 + wr * 64;
        int b_ = mrow >> 10, sr0 = mrow & 1023;
        unsigned short* ob = out + ((size_t)((b_ * HH + h) << 10) + sr0) * HDIM;
        #pragma unroll
        for (int u = 0; u < 8; ++u) {
            int s = lane + u * 64;
            int row = s >> 3, c8 = s & 7;
            uint4 v = *reinterpret_cast<const uint4*>(&S[row * 76 + c8 * 8]);
            *reinterpret_cast<uint4*>(ob + row * HDIM + c8 * 8) = v;
        }
    }
}

// ================= Kernel 3: flash attention (round-3 version) =============
// 64 q-rows/block, 4 waves x 16 rows, Kt=64. Transposed score MFMA (St=K*Q^T)
// so each thread owns 4 consecutive keys -> b64 P-stores, scalar lsum.
// Double-buffered global_load_lds staging, ONE barrier/iter.
__global__ __launch_bounds__(256) void attention(
    const unsigned short* __restrict__ q,     // [bh][s][hd]
    const unsigned short* __restrict__ k,     // [bh][s][hd]
    const unsigned short* __restrict__ vt,    // [bh][hd][s]
    const float* __restrict__ mask,
    float* __restrict__ out)
{
    __shared__ unsigned short Ks[2][64 * 64];     // [key][hd], swizzled chunks
    __shared__ unsigned short Vs[2][64 * 64];     // [hd][key], swizzled chunks
    __shared__ unsigned short Ps[4][16 * 72];     // per-wave P[qrow][key], stride 72
    __shared__ float msk[SS];                     // mask * log2(e)

    // XCD swizzle: all 16 q-tiles of a (b,h) on one XCD
    int blk = blockIdx.x;
    int xcd = blk & 7, j = blk >> 3;
    int bh = (xcd << 4) + (j >> 4);
    int qt = j & 15;
    int b = bh >> 4, h = bh & 15;

    int tid = threadIdx.x;
    int wave = tid >> 6, lane = tid & 63, lq = lane >> 4, lm = lane & 15;

    const unsigned short* qp = q + (size_t)bh * SS * HDIM;
    const unsigned short* kp = k + (size_t)bh * SS * HDIM;
    const unsigned short* vp = vt + (size_t)bh * HDIM * SS;

    for (int i = tid; i < SS; i += 256) msk[i] = mask[b * SS + i] * 1.44269504f;

    // Q fragments (B-operand: B[k=lq*8+j][n=lm] = Q[qrow=lm][hd=lq*8+j])
    int qrow = qt * 64 + wave * 16 + lm;
    bf16x8 qa0 = *reinterpret_cast<const bf16x8*>(qp + qrow * HDIM + lq * 8);
    bf16x8 qa1 = *reinterpret_cast<const bf16x8*>(qp + qrow * HDIM + 32 + lq * 8);

    float lsum = 0.f;
    f32x4 o[4] = {};

    // staging: slot tid -> (row=tid>>3, s=tid&7); +256 -> row+32
    int row0 = tid >> 3, sg = tid & 7;
    int cg = (sg - row0) & 7;                     // chunk swizzle (c + row) & 7
    const unsigned short* gk = kp + row0 * 64 + cg * 8;
    const unsigned short* gv = vp + row0 * SS + cg * 8;

    int sl0 = ((lq + lm) & 7) * 8;                // frag-read swizzled offsets
    int sl1 = ((lq + lm + 4) & 7) * 8;

    async16(&Ks[0][tid * 8], gk);  async16(&Ks[0][(tid + 256) * 8], gk + 32 * 64);
    async16(&Vs[0][tid * 8], gv);  async16(&Vs[0][(tid + 256) * 8], gv + 32 * SS);
    gk += 64 * 64; gv += 64;

    unsigned short* Pw = Ps[wave];

    for (int t = 0; t < 16; ++t) {
        int p = t & 1;
        __syncthreads();
        if (t < 15) {
            async16(&Ks[p ^ 1][tid * 8], gk);  async16(&Ks[p ^ 1][(tid + 256) * 8], gk + 32 * 64);
            async16(&Vs[p ^ 1][tid * 8], gv);  async16(&Vs[p ^ 1][(tid + 256) * 8], gv + 32 * SS);
            gk += 64 * 64; gv += 64;
        }
        int kb0 = t * 64;

        // St = K * Q^T: 4 key-blocks (M=16 keys each), K-dim=64 in 2 steps
        f32x4 c[4];
        #pragma unroll
        for (int nb = 0; nb < 4; ++nb) {
            bf16x8 kf0 = *reinterpret_cast<const bf16x8*>(&Ks[p][(nb * 16 + lm) * 64 + sl0]);
            bf16x8 kf1 = *reinterpret_cast<const bf16x8*>(&Ks[p][(nb * 16 + lm) * 64 + sl1]);
            f32x4 z = {};
            z = __builtin_amdgcn_mfma_f32_16x16x32_bf16(kf0, qa0, z, 0, 0, 0);
            z = __builtin_amdgcn_mfma_f32_16x16x32_bf16(kf1, qa1, z, 0, 0, 0);
            c[nb] = z;
        }

        // softmax piece: thread owns keys nb*16+lq*4+r, qrow=lm
        #pragma unroll
        for (int nb = 0; nb < 4; ++nb) {
            float4 mk = *reinterpret_cast<const float4*>(&msk[kb0 + nb * 16 + lq * 4]);
            unsigned u[4];
            #pragma unroll
            for (int r = 0; r < 4; ++r) {
                float e = exp2fast(fmaf(c[nb][r], 0.18033688f,
                                        reinterpret_cast<const float*>(&mk)[r]));
                union { float f; unsigned v; } cv; cv.f = e;
                u[r] = cv.v;
                union { unsigned v; float f; } tr; tr.v = cv.v & 0xffff0000u;
                lsum += tr.f;                      // lsum of TRUNCATED p: exact cancel
            }
            uint2 pk;
            pk.x = __builtin_amdgcn_perm(u[1], u[0], 0x07060302u);
            pk.y = __builtin_amdgcn_perm(u[3], u[2], 0x07060302u);
            *reinterpret_cast<uint2*>(&Pw[lm * 72 + nb * 16 + lq * 4]) = pk;
        }

        // O += P*V (P wave-private, same-wave DS ops are in-order)
        #pragma unroll
        for (int ks = 0; ks < 2; ++ks) {
            bf16x8 pa = *reinterpret_cast<const bf16x8*>(&Pw[lm * 72 + ks * 32 + lq * 8]);
            int slv = (ks == 0) ? sl0 : sl1;
            #pragma unroll
            for (int nb2 = 0; nb2 < 4; ++nb2) {
                bf16x8 vf = *reinterpret_cast<const bf16x8*>(&Vs[p][(nb2 * 16 + lm) * 64 + slv]);
                o[nb2] = __builtin_amdgcn_mfma_f32_16x16x32_bf16(pa, vf, o[nb2], 0, 0, 0);
            }
        }
    }

    // lsum (q=lm) lives in 4 lq-copies: reduce across lq, fetch per out-row
    lsum += __shfl_xor(lsum, 16, 64);
    lsum += __shfl_xor(lsum, 32, 64);
    float linv[4];
    #pragma unroll
    for (int r = 0; r < 4; ++r)
        linv[r] = 1.0f / __shfl(lsum, lq * 4 + r, 64);

    #pragma unroll
    for (int nb2 = 0; nb2 < 4; ++nb2) {
        #pragma unroll
        for (int r = 0; r < 4; ++r) {
            int sr = qt * 64 + wave * 16 + lq * 4 + r;
            out[((size_t)(b * SS + sr)) * DD + h * HDIM + nb2 * 16 + lm] = o[nb2][r] * linv[r];
        }
    }
}

extern "C" void kernel_launch(void* const* d_in, const int* in_sizes, int n_in,
                              void* d_out, int out_size, void* d_ws, size_t ws_size,
                              hipStream_t stream) {
    const float* hs   = (const float*)d_in[0];
    const float* mask = (const float*)d_in[1];
    const float* Wq   = (const float*)d_in[2];
    const float* bq   = (const float*)d_in[3];
    const float* Wk   = (const float*)d_in[4];
    const float* bk   = (const float*)d_in[5];
    const float* Wv   = (const float*)d_in[6];
    const float* bv   = (const float*)d_in[7];
    float* out = (float*)d_out;

    char* ws = (char*)d_ws;
    // ws layout (bytes): XF 16MB | WF0/1/2 2MB each | q,k,vt 16MB each = 70MB
    unsigned short* XF  = (unsigned short*)(ws);
    unsigned short* WF0 = (unsigned short*)(ws + 16777216);
    unsigned short* WF1 = (unsigned short*)(ws + 18874368);
    unsigned short* WF2 = (unsigned short*)(ws + 20971520);
    unsigned short* qw  = (unsigned short*)(ws + 23068672);
    unsigned short* kw  = (unsigned short*)(ws + 39845888);
    unsigned short* vtw = (unsigned short*)(ws + 56623104);

    prep<<<2816, 256, 0, stream>>>(hs, XF, Wq, Wk, Wv, WF0, WF1, WF2);
    gemm_qkv<<<1536, 256, 0, stream>>>(XF, WF0, WF1, WF2,
                                       bq, bk, bv, qw, kw, vtw);
    attention<<<2048, 256, 0, stream>>>(qw, kw, vtw, mask, out);
}

// Round 6
// 218.237 us; speedup vs baseline: 1.2867x; 1.0659x over previous
//
#include <hip/hip_runtime.h>
#include <stdint.h>

// Problem constants: B=8, S=1024, D=1024, H=16, HD=64
#define BB 8
#define SS 1024
#define DD 1024
#define HH 16
#define HDIM 64

typedef __bf16 bf16x8 __attribute__((ext_vector_type(8)));
typedef float f32x4 __attribute__((ext_vector_type(4)));

__device__ __forceinline__ unsigned short f2bf(float f) {
    union { float f; unsigned u; } v; v.f = f;
    unsigned r = v.u + 0x7fff + ((v.u >> 16) & 1);   // RNE
    return (unsigned short)(r >> 16);
}

__device__ __forceinline__ float exp2fast(float x) {
#if __has_builtin(__builtin_amdgcn_exp2f)
    return __builtin_amdgcn_exp2f(x);
#else
    return __expf(x * 0.69314718f);
#endif
}

// async global->LDS, 16B per lane (LDS dest: wave-uniform base + lane*16)
__device__ __forceinline__ void async16(void* lds, const void* g) {
    __builtin_amdgcn_global_load_lds(
        (const __attribute__((address_space(1))) unsigned int*)g,
        (__attribute__((address_space(3))) unsigned int*)lds, 16, 0, 0);
}

// ================= Kernel 1: prep (unchanged r5) =================
__global__ __launch_bounds__(256) void prep(
    const float* __restrict__ x, unsigned short* __restrict__ xf,
    const float* __restrict__ w0, const float* __restrict__ w1,
    const float* __restrict__ w2,
    unsigned short* __restrict__ f0, unsigned short* __restrict__ f1,
    unsigned short* __restrict__ f2)
{
    __shared__ unsigned short tile[64 * 76];
    int bid = blockIdx.x;
    int tid = threadIdx.x;
    if (bid < 2048) {
        int mt = bid >> 4, kt = bid & 15;
        const float* src = x + (size_t)(mt * 64) * DD + kt * 64;
        #pragma unroll
        for (int i = 0; i < 4; ++i) {
            int f = tid + i * 256;              // 64 rows x 16 float4
            int r = f >> 4, c4 = f & 15;
            float4 v = *reinterpret_cast<const float4*>(src + r * DD + c4 * 4);
            ushort4 o;
            o.x = f2bf(v.x); o.y = f2bf(v.y); o.z = f2bf(v.z); o.w = f2bf(v.w);
            *reinterpret_cast<ushort4*>(&tile[r * 76 + c4 * 4]) = o;
        }
        __syncthreads();
        #pragma unroll
        for (int i = 0; i < 2; ++i) {
            int s = tid + i * 256;
            int frag = s >> 6, l = s & 63;
            int m_l = (frag & 3) * 16 + (l & 15);
            int k_l = (frag >> 2) * 32 + ((l >> 4) & 3) * 8;
            uint4 v = *reinterpret_cast<const uint4*>(&tile[m_l * 76 + k_l]);
            int fm = mt * 4 + (frag & 3);
            int fk = kt * 2 + (frag >> 2);
            *reinterpret_cast<uint4*>(xf + (size_t)((fm * 32 + fk) * 64 + l) * 8) = v;
        }
        return;
    }
    int idx = bid - 2048;                       // 0..767
    int z = idx >> 8, rem = idx & 255;
    const float* w = (z == 0) ? w0 : (z == 1) ? w1 : w2;
    unsigned short* wf = (z == 0) ? f0 : (z == 1) ? f1 : f2;
    int kt = rem & 15, nt = rem >> 4;
    const float* src = w + (size_t)(kt * 64) * DD + nt * 64;
    #pragma unroll
    for (int i = 0; i < 4; ++i) {
        int f = tid + i * 256;
        int r = f >> 4, c4 = f & 15;            // r = k, c4 = n/4
        float4 v = *reinterpret_cast<const float4*>(src + r * DD + c4 * 4);
        ushort4 o;
        o.x = f2bf(v.x); o.y = f2bf(v.y); o.z = f2bf(v.z); o.w = f2bf(v.w);
        *reinterpret_cast<ushort4*>(&tile[r * 76 + c4 * 4]) = o;
    }
    __syncthreads();
    #pragma unroll
    for (int i = 0; i < 2; ++i) {
        int s = tid + i * 256;
        int frag = s >> 6, l = s & 63;
        int n_l = (frag & 3) * 16 + (l & 15);
        int k_l = (frag >> 2) * 32 + ((l >> 4) & 3) * 8;
        unsigned short tmp[8];
        #pragma unroll
        for (int j = 0; j < 8; ++j) tmp[j] = tile[(k_l + j) * 76 + n_l];
        int fn = nt * 4 + (frag & 3);
        int fk = kt * 2 + (frag >> 2);
        *reinterpret_cast<uint4*>(wf + (size_t)((fn * 32 + fk) * 64 + l) * 8) =
            *reinterpret_cast<const uint4*>(tmp);
    }
}

// ================= Kernel 2: fused QKV GEMM (unchanged r5) =================
__global__ __launch_bounds__(256, 3) void gemm_qkv(
    const unsigned short* __restrict__ xf,
    const unsigned short* __restrict__ wf0, const unsigned short* __restrict__ wf1,
    const unsigned short* __restrict__ wf2,
    const float* __restrict__ b0, const float* __restrict__ b1, const float* __restrict__ b2,
    unsigned short* __restrict__ qo, unsigned short* __restrict__ ko,
    unsigned short* __restrict__ vto)
{
    int bid = blockIdx.x;
    int xcd = bid & 7, g = bid >> 3;           // g 0..191
    int strip = xcd * 3 + (g % 3);             // 0..23
    int mt = g / 3;                            // 0..63
    int nt = strip & 7, z = strip >> 3;

    const unsigned short* wf; const float* bias; unsigned short* out;
    if (z == 0)      { wf = wf0; bias = b0; out = qo; }
    else if (z == 1) { wf = wf1; bias = b1; out = ko; }
    else             { wf = wf2; bias = b2; out = vto; }

    __shared__ unsigned short stg[4][64 * 76];  // epilogue staging only

    int tid = threadIdx.x;
    int wave = tid >> 6, lane = tid & 63, lq = lane >> 4, lm = lane & 15;
    int wr = wave >> 1, wc = wave & 1;

    const unsigned short* aB = xf + (size_t)((mt * 8 + wr * 4) * 32) * 512 + lane * 8;
    const unsigned short* bB = wf + (size_t)((nt * 8 + wc * 4) * 32) * 512 + lane * 8;

    f32x4 acc[4][4] = {};
    bf16x8 a0[4], a1[4], bb0[4], bb1[4];

#define LDFRAGS(AB, BB, T)                                                     \
    {                                                                          \
        _Pragma("unroll") for (int i_ = 0; i_ < 4; ++i_)                       \
            AB[i_] = *reinterpret_cast<const bf16x8*>(aB + (i_ * 32 + (T)) * 512); \
        _Pragma("unroll") for (int j_ = 0; j_ < 4; ++j_)                       \
            BB[j_] = *reinterpret_cast<const bf16x8*>(bB + (j_ * 32 + (T)) * 512); \
    }
#define MFMAS(AB, BB)                                                          \
    {                                                                          \
        _Pragma("unroll") for (int i_ = 0; i_ < 4; ++i_)                       \
            _Pragma("unroll") for (int j_ = 0; j_ < 4; ++j_)                   \
                acc[i_][j_] = __builtin_amdgcn_mfma_f32_16x16x32_bf16(         \
                    AB[i_], BB[j_], acc[i_][j_], 0, 0, 0);                     \
    }

    LDFRAGS(a0, bb0, 0);
    for (int tt = 0; tt < 16; ++tt) {
        int t = tt * 2;
        LDFRAGS(a1, bb1, t + 1);
        MFMAS(a0, bb0);
        LDFRAGS(a0, bb0, t + 2);   // tt=15 loads t=32: harmless in-ws garbage, unused
        MFMAS(a1, bb1);
    }
#undef LDFRAGS
#undef MFMAS

    int m0 = mt * 128;
    int col0 = nt * 128 + wc * 64;              // wave's 64-col block = one head
    if (z == 2) {
        #pragma unroll
        for (int j = 0; j < 4; ++j) {
            int col = col0 + j * 16 + lm;
            float bsv = bias[col];
            int h = col >> 6, hd = col & 63;
            #pragma unroll
            for (int i = 0; i < 4; ++i) {
                int m = m0 + wr * 64 + i * 16 + lq * 4;
                int b_ = m >> 10, sr = m & 1023;
                union { float f; unsigned u; } p0, p1, p2, p3;
                p0.f = acc[i][j][0] + bsv; p1.f = acc[i][j][1] + bsv;
                p2.f = acc[i][j][2] + bsv; p3.f = acc[i][j][3] + bsv;
                uint2 pk;
                pk.x = __builtin_amdgcn_perm(p1.u + 0x8000u, p0.u + 0x8000u, 0x07060302u);
                pk.y = __builtin_amdgcn_perm(p3.u + 0x8000u, p2.u + 0x8000u, 0x07060302u);
                *reinterpret_cast<uint2*>(out + (((b_ * HH + h) * HDIM + hd) << 10) + sr) = pk;
            }
        }
    } else {
        unsigned short* S = stg[wave];
        #pragma unroll
        for (int j = 0; j < 4; ++j) {
            float bsv = bias[col0 + j * 16 + lm];
            #pragma unroll
            for (int i = 0; i < 4; ++i) {
                #pragma unroll
                for (int r = 0; r < 4; ++r) {
                    union { float f; unsigned u; } cv; cv.f = acc[i][j][r] + bsv;
                    S[(i * 16 + lq * 4 + r) * 76 + j * 16 + lm] =
                        (unsigned short)((cv.u + 0x8000u) >> 16);
                }
            }
        }
        int h = col0 >> 6;
        int mrow = m0 + wr * 64;
        int b_ = mrow >> 10, sr0 = mrow & 1023;
        unsigned short* ob = out + ((size_t)((b_ * HH + h) << 10) + sr0) * HDIM;
        #pragma unroll
        for (int u = 0; u < 8; ++u) {
            int s = lane + u * 64;
            int row = s >> 3, c8 = s & 7;
            uint4 v = *reinterpret_cast<const uint4*>(&S[row * 76 + c8 * 8]);
            *reinterpret_cast<uint4*>(ob + row * HDIM + c8 * 8) = v;
        }
    }
}

// ================= Kernel 3: flash attention v6 =================
// 128 q-rows/block (2 strips of 16 per wave, 64 apart), Kt=64, 16 iters.
// Shared Ks/Vs fragment reads feed BOTH strips; single Ps region reused via
// in-order DS sequencing (Pw0 -> pa0 reads -> Pw1 -> pa1 reads -> shared-vf PV).
// LDS = 40KB exactly -> 4 blocks/CU. Mask loaded from global BEFORE the
// async16 prefetch so its vmcnt wait doesn't drain the prefetch queue.
__global__ __launch_bounds__(256, 4) void attention(
    const unsigned short* __restrict__ q,     // [bh][s][hd]
    const unsigned short* __restrict__ k,     // [bh][s][hd]
    const unsigned short* __restrict__ vt,    // [bh][hd][s]
    const float* __restrict__ mask,
    float* __restrict__ out)
{
    __shared__ unsigned short Ks[2][64 * 64];   // [key][hd], swizzled chunks
    __shared__ unsigned short Vs[2][64 * 64];   // [hd][key], swizzled chunks
    __shared__ unsigned short Ps[4][16 * 64];   // per-wave P[q][key], swizzled

    // XCD swizzle: all 8 q-tiles of a (b,h) on one XCD
    int blk = blockIdx.x;
    int xcd = blk & 7, j = blk >> 3;            // j 0..127
    int bh = (xcd << 4) + (j >> 3);
    int qt = j & 7;
    int b = bh >> 4, h = bh & 15;

    int tid = threadIdx.x;
    int wave = tid >> 6, lane = tid & 63, lq = lane >> 4, lm = lane & 15;

    const unsigned short* qp = q + (size_t)bh * SS * HDIM;
    const unsigned short* kp = k + (size_t)bh * SS * HDIM;
    const unsigned short* vp = vt + (size_t)bh * HDIM * SS;
    const float* maskb = mask + b * SS;

    // Q fragments for both strips (B-operand: B[k=lq*8+j][n=lm])
    int qbase = qt * 128 + wave * 16 + lm;
    bf16x8 qa00 = *reinterpret_cast<const bf16x8*>(qp + qbase * HDIM + lq * 8);
    bf16x8 qa01 = *reinterpret_cast<const bf16x8*>(qp + qbase * HDIM + 32 + lq * 8);
    bf16x8 qa10 = *reinterpret_cast<const bf16x8*>(qp + (qbase + 64) * HDIM + lq * 8);
    bf16x8 qa11 = *reinterpret_cast<const bf16x8*>(qp + (qbase + 64) * HDIM + 32 + lq * 8);

    float lsum0 = 0.f, lsum1 = 0.f;
    f32x4 o0[4] = {}, o1[4] = {};

    // staging: slot tid -> (row=tid>>3, s=tid&7); +256 -> row+32
    int row0 = tid >> 3, sg = tid & 7;
    int cg = (sg - row0) & 7;                   // chunk swizzle (c + row) & 7
    const unsigned short* gk = kp + row0 * 64 + cg * 8;
    const unsigned short* gv = vp + row0 * SS + cg * 8;

    int sl0 = ((lq + lm) & 7) * 8;              // Ks/Vs frag swizzled offsets
    int sl1 = ((lq + lm + 4) & 7) * 8;
    unsigned short* Pw = Ps[wave];
    int pwbase = lm * 64 + (lq & 1) * 4;        // P-write: chunk nb*2+(lq>>1)
    int prd0 = lm * 64 + sl0;                   // P-read chunk lq (ks=0)
    int prd1 = lm * 64 + sl1;                   // P-read chunk 4+lq (ks=1)

    async16(&Ks[0][tid * 8], gk);  async16(&Ks[0][(tid + 256) * 8], gk + 32 * 64);
    async16(&Vs[0][tid * 8], gv);  async16(&Vs[0][(tid + 256) * 8], gv + 32 * SS);
    gk += 64 * 64; gv += 64;

    for (int t = 0; t < 16; ++t) {
        int p = t & 1;
        __syncthreads();
        int kb0 = t * 64;

        // mask (L2-hot) BEFORE prefetch: its vmcnt wait tolerates the asyncs
        float4 mk[4];
        #pragma unroll
        for (int nb = 0; nb < 4; ++nb) {
            mk[nb] = *reinterpret_cast<const float4*>(maskb + kb0 + nb * 16 + lq * 4);
            #pragma unroll
            for (int r = 0; r < 4; ++r)
                reinterpret_cast<float*>(&mk[nb])[r] *= 1.44269504f;
        }
        if (t < 15) {
            async16(&Ks[p ^ 1][tid * 8], gk);  async16(&Ks[p ^ 1][(tid + 256) * 8], gk + 32 * 64);
            async16(&Vs[p ^ 1][tid * 8], gv);  async16(&Vs[p ^ 1][(tid + 256) * 8], gv + 32 * SS);
            gk += 64 * 64; gv += 64;
        }

        // 1. scores for BOTH strips off one Ks read
        f32x4 c0[4], c1[4];
        #pragma unroll
        for (int nb = 0; nb < 4; ++nb) {
            bf16x8 kf0 = *reinterpret_cast<const bf16x8*>(&Ks[p][(nb * 16 + lm) * 64 + sl0]);
            bf16x8 kf1 = *reinterpret_cast<const bf16x8*>(&Ks[p][(nb * 16 + lm) * 64 + sl1]);
            f32x4 z = {};
            z = __builtin_amdgcn_mfma_f32_16x16x32_bf16(kf0, qa00, z, 0, 0, 0);
            z = __builtin_amdgcn_mfma_f32_16x16x32_bf16(kf1, qa01, z, 0, 0, 0);
            c0[nb] = z;
            f32x4 w = {};
            w = __builtin_amdgcn_mfma_f32_16x16x32_bf16(kf0, qa10, w, 0, 0, 0);
            w = __builtin_amdgcn_mfma_f32_16x16x32_bf16(kf1, qa11, w, 0, 0, 0);
            c1[nb] = w;
        }

        // 2. exp strip0 + P-writes
        #pragma unroll
        for (int nb = 0; nb < 4; ++nb) {
            unsigned u[4];
            #pragma unroll
            for (int r = 0; r < 4; ++r) {
                float e = exp2fast(fmaf(c0[nb][r], 0.18033688f,
                                        reinterpret_cast<const float*>(&mk[nb])[r]));
                union { float f; unsigned v; } cv; cv.f = e;
                u[r] = cv.v;
                union { unsigned v; float f; } tr; tr.v = cv.v & 0xffff0000u;
                lsum0 += tr.f;                  // lsum of TRUNCATED p: exact cancel
            }
            uint2 pk;
            pk.x = __builtin_amdgcn_perm(u[1], u[0], 0x07060302u);
            pk.y = __builtin_amdgcn_perm(u[3], u[2], 0x07060302u);
            *reinterpret_cast<uint2*>(
                &Pw[pwbase + (((nb * 2 + (lq >> 1)) + lm) & 7) * 8]) = pk;
        }
        // 3. strip0 P A-frags into regs (in-order after the writes)
        bf16x8 pa00 = *reinterpret_cast<const bf16x8*>(&Pw[prd0]);
        bf16x8 pa01 = *reinterpret_cast<const bf16x8*>(&Pw[prd1]);

        // 4. exp strip1 + P-writes (overwrite Ps AFTER strip0 reads: in-order)
        #pragma unroll
        for (int nb = 0; nb < 4; ++nb) {
            unsigned u[4];
            #pragma unroll
            for (int r = 0; r < 4; ++r) {
                float e = exp2fast(fmaf(c1[nb][r], 0.18033688f,
                                        reinterpret_cast<const float*>(&mk[nb])[r]));
                union { float f; unsigned v; } cv; cv.f = e;
                u[r] = cv.v;
                union { unsigned v; float f; } tr; tr.v = cv.v & 0xffff0000u;
                lsum1 += tr.f;
            }
            uint2 pk;
            pk.x = __builtin_amdgcn_perm(u[1], u[0], 0x07060302u);
            pk.y = __builtin_amdgcn_perm(u[3], u[2], 0x07060302u);
            *reinterpret_cast<uint2*>(
                &Pw[pwbase + (((nb * 2 + (lq >> 1)) + lm) & 7) * 8]) = pk;
        }
        // 5. strip1 P A-frags
        bf16x8 pa10 = *reinterpret_cast<const bf16x8*>(&Pw[prd0]);
        bf16x8 pa11 = *reinterpret_cast<const bf16x8*>(&Pw[prd1]);

        // 6. PV: each Vs read feeds BOTH strips
        #pragma unroll
        for (int nb2 = 0; nb2 < 4; ++nb2) {
            bf16x8 vf0 = *reinterpret_cast<const bf16x8*>(&Vs[p][(nb2 * 16 + lm) * 64 + sl0]);
            o0[nb2] = __builtin_amdgcn_mfma_f32_16x16x32_bf16(pa00, vf0, o0[nb2], 0, 0, 0);
            o1[nb2] = __builtin_amdgcn_mfma_f32_16x16x32_bf16(pa10, vf0, o1[nb2], 0, 0, 0);
            bf16x8 vf1 = *reinterpret_cast<const bf16x8*>(&Vs[p][(nb2 * 16 + lm) * 64 + sl1]);
            o0[nb2] = __builtin_amdgcn_mfma_f32_16x16x32_bf16(pa01, vf1, o0[nb2], 0, 0, 0);
            o1[nb2] = __builtin_amdgcn_mfma_f32_16x16x32_bf16(pa11, vf1, o1[nb2], 0, 0, 0);
        }
    }

    // reduce lsum (per qrow=lm, 4 lq-copies) and write both strips
    lsum0 += __shfl_xor(lsum0, 16, 64);
    lsum0 += __shfl_xor(lsum0, 32, 64);
    lsum1 += __shfl_xor(lsum1, 16, 64);
    lsum1 += __shfl_xor(lsum1, 32, 64);
    float linv0[4], linv1[4];
    #pragma unroll
    for (int r = 0; r < 4; ++r) {
        linv0[r] = 1.0f / __shfl(lsum0, lq * 4 + r, 64);
        linv1[r] = 1.0f / __shfl(lsum1, lq * 4 + r, 64);
    }

    int srb = qt * 128 + wave * 16;
    #pragma unroll
    for (int nb2 = 0; nb2 < 4; ++nb2) {
        #pragma unroll
        for (int r = 0; r < 4; ++r) {
            int sr = srb + lq * 4 + r;
            out[((size_t)(b * SS + sr)) * DD + h * HDIM + nb2 * 16 + lm] =
                o0[nb2][r] * linv0[r];
            out[((size_t)(b * SS + sr + 64)) * DD + h * HDIM + nb2 * 16 + lm] =
                o1[nb2][r] * linv1[r];
        }
    }
}

extern "C" void kernel_launch(void* const* d_in, const int* in_sizes, int n_in,
                              void* d_out, int out_size, void* d_ws, size_t ws_size,
                              hipStream_t stream) {
    const float* hs   = (const float*)d_in[0];
    const float* mask = (const float*)d_in[1];
    const float* Wq   = (const float*)d_in[2];
    const float* bq   = (const float*)d_in[3];
    const float* Wk   = (const float*)d_in[4];
    const float* bk   = (const float*)d_in[5];
    const float* Wv   = (const float*)d_in[6];
    const float* bv   = (const float*)d_in[7];
    float* out = (float*)d_out;

    char* ws = (char*)d_ws;
    // ws layout (bytes): XF 16MB | WF0/1/2 2MB each | q,k,vt 16MB each = 70MB
    unsigned short* XF  = (unsigned short*)(ws);
    unsigned short* WF0 = (unsigned short*)(ws + 16777216);
    unsigned short* WF1 = (unsigned short*)(ws + 18874368);
    unsigned short* WF2 = (unsigned short*)(ws + 20971520);
    unsigned short* qw  = (unsigned short*)(ws + 23068672);
    unsigned short* kw  = (unsigned short*)(ws + 39845888);
    unsigned short* vtw = (unsigned short*)(ws + 56623104);

    prep<<<2816, 256, 0, stream>>>(hs, XF, Wq, Wk, Wv, WF0, WF1, WF2);
    gemm_qkv<<<1536, 256, 0, stream>>>(XF, WF0, WF1, WF2,
                                       bq, bk, bv, qw, kw, vtw);
    attention<<<1024, 256, 0, stream>>>(qw, kw, vtw, mask, out);
}